// Round 23
// baseline (95.425 us; speedup 1.0000x reference)
//
#include <hip/hip_runtime.h>

// Chamfer distance loss via uniform-grid NN, cooperative W-lane queries,
// certified ring-1 search + segmented wave-task brute-force fallback.
// N=65536 vertices (x), M=8192 samples (y), D=3, points ~ N(0,1)^3.
// l1 = sum_m probs[m] * min_n d2(n,m);  l2 = sum_n probs[argmin_m] * min_m d2.
//
// R22 champion (93.2 us) + two deltas:
//  (1) rows W=8->16 (row chain 33->16 dependent L2 loads; same lever that
//      won cols W=64 in R22), RBLK 2048->4096
//  (2) scan_b folded into scan_c (each block redundantly scans the 256 block
//      sums in LDS) -- one fewer dispatch.
// Ledger of regressions: z-slab -35, stealing -200, dual-load -7, 1-blk scan -5.
//
// Grid: K=32 per dim over [-R0,R0), H=0.265625. Both sets counting-sorted into
// one float4 array (x cells [0,KC), y cells [KC,2KC)); .w = original index.
// NN scan: 27 cells as 9 contiguous runs; W lanes stride each run, shfl_xor min.
// Certification: thr = exact distance to scanned-box boundary, edge-open axes.
// Uncertified (Gaussian tail) -> compacted list -> segmented wave-task brute
// force (exact, atomicMin merge). Rows key = (d2bits & ~0x1FFF) | m.

constexpr int NP = 65536;
constexpr int MP = 8192;
constexpr int K = 32;
constexpr int KC = K * K * K;            // 32768 cells per set
constexpr float H = 0.265625f;           // 8.5/32, exact in fp32
constexpr float R0 = 4.25f;

// ws layout (bytes):
constexpr size_t OFF_CNT    = 0;                      // u32[2*KC]
constexpr size_t OFF_FBCNT  = 262144;                 // u32[2] (+pad)
constexpr size_t OFF_PART   = 262160;                 // u32[2*KC], reused as cursor
constexpr size_t OFF_OFFS   = 524304;                 // u32[2*KC+1] (+pad)
constexpr size_t OFF_BSUM   = 786464;                 // u32[256]
constexpr size_t OFF_FBROW  = 787488;                 // u32[NP]
constexpr size_t OFF_FBCOL  = 1049632;                // u32[MP]
constexpr size_t OFF_ROWKEY = 1082400;                // u32[NP]
constexpr size_t OFF_COLBIT = 1344544;                // u32[MP]
constexpr size_t OFF_PTS    = 1377312;                // float4[NP+MP] (16B aligned)

__device__ __forceinline__ int cellof(float v) {
    int c = (int)floorf((v + R0) * (1.0f / H));
    return min(max(c, 0), K - 1);
}
__device__ __forceinline__ unsigned umin32(unsigned a, unsigned b) { return a < b ? a : b; }

__global__ __launch_bounds__(256) void k_count(const float* __restrict__ x,
                                               const float* __restrict__ y,
                                               unsigned* __restrict__ cnt,
                                               unsigned* __restrict__ fbcnt,
                                               float* __restrict__ out) {
    int i = blockIdx.x * 256 + threadIdx.x;
    if (i == 0) { fbcnt[0] = 0; fbcnt[1] = 0; out[0] = 0.f; }
    if (i < NP) {
        int c = (cellof(x[3 * i + 2]) * K + cellof(x[3 * i + 1])) * K + cellof(x[3 * i]);
        atomicAdd(&cnt[c], 1u);
    } else if (i < NP + MP) {
        int j = i - NP;
        int c = (cellof(y[3 * j + 2]) * K + cellof(y[3 * j + 1])) * K + cellof(y[3 * j]);
        atomicAdd(&cnt[KC + c], 1u);
    }
}

__global__ __launch_bounds__(256) void k_scan_a(const unsigned* __restrict__ cnt,
                                                unsigned* __restrict__ part,
                                                unsigned* __restrict__ bsum) {
    int t = threadIdx.x;
    int g = blockIdx.x * 256 + t;
    unsigned v = cnt[g];
    unsigned inc = v;
#pragma unroll
    for (int o = 1; o < 64; o <<= 1) {
        unsigned u = __shfl_up(inc, o, 64);
        if ((t & 63) >= o) inc += u;
    }
    __shared__ unsigned wtot[4];
    if ((t & 63) == 63) wtot[t >> 6] = inc;
    __syncthreads();
    unsigned woff = 0;
    for (int w = 0; w < (t >> 6); ++w) woff += wtot[w];
    part[g] = woff + inc - v;
    if (t == 255) bsum[blockIdx.x] = woff + inc;
}

// scan_c with scan_b folded in: every block redundantly block-scans the 256
// block sums into LDS, then adds its own prefix.
__global__ __launch_bounds__(256) void k_scan_c(const unsigned* __restrict__ cnt,
                                                unsigned* __restrict__ part,
                                                unsigned* __restrict__ offs,
                                                const unsigned* __restrict__ bsum) {
    int t = threadIdx.x;
    int g = blockIdx.x * 256 + t;
    __shared__ unsigned spre[256];
    {
        unsigned v = bsum[t];
        unsigned inc = v;
#pragma unroll
        for (int o = 1; o < 64; o <<= 1) {
            unsigned u = __shfl_up(inc, o, 64);
            if ((t & 63) >= o) inc += u;
        }
        __shared__ unsigned wtot[4];
        if ((t & 63) == 63) wtot[t >> 6] = inc;
        __syncthreads();
        unsigned woff = 0;
        for (int w = 0; w < (t >> 6); ++w) woff += wtot[w];
        spre[t] = woff + inc - v;  // exclusive prefix of bsum
        __syncthreads();
    }
    unsigned off = part[g] + spre[blockIdx.x];
    offs[g] = off;
    part[g] = off;  // cursor for scatter
    if (g == 2 * KC - 1) offs[2 * KC] = off + cnt[g];
}

__global__ __launch_bounds__(256) void k_scatter(const float* __restrict__ x,
                                                 const float* __restrict__ y,
                                                 unsigned* __restrict__ cursor,
                                                 float4* __restrict__ pts) {
    int i = blockIdx.x * 256 + threadIdx.x;
    if (i < NP) {
        float a = x[3 * i], b = x[3 * i + 1], c = x[3 * i + 2];
        int cc = (cellof(c) * K + cellof(b)) * K + cellof(a);
        unsigned s = atomicAdd(&cursor[cc], 1u);
        pts[s] = make_float4(a, b, c, __uint_as_float((unsigned)i));
    } else if (i < NP + MP) {
        int j = i - NP;
        float a = y[3 * j], b = y[3 * j + 1], c = y[3 * j + 2];
        int cc = (cellof(c) * K + cellof(b)) * K + cellof(a);
        unsigned s = atomicAdd(&cursor[KC + cc], 1u);
        pts[s] = make_float4(a, b, c, __uint_as_float((unsigned)j));
    }
}

// Cooperative NN body: W lanes per query, queries from the cell-sorted pts
// array (W-groups in a wave share a cell -> aligned runs, coalesced loads).
// ROWS: x-queries scan y-cells, packed key with m. COLS: y-queries, d2 bits.
template <int W, bool ROWS>
__device__ __forceinline__ void nn_body(int bid, const float4* __restrict__ pts,
                                        const unsigned* __restrict__ offs,
                                        unsigned* __restrict__ outv,
                                        unsigned* __restrict__ fbcnt,
                                        unsigned* __restrict__ fblist) {
    int t = threadIdx.x;
    int lane = t & (W - 1);
    int q = (bid * 256 + t) / W;
    float4 Q = pts[(ROWS ? 0 : NP) + q];
    unsigned qi = __float_as_uint(Q.w);  // original n (rows) or m (cols)
    int cx = cellof(Q.x), cy = cellof(Q.y), cz = cellof(Q.z);
    int x0c = max(cx - 1, 0), x1c = min(cx + 1, K - 1);
    int span = x1c - x0c + 1;
    constexpr int base = ROWS ? KC : 0;
    unsigned best = 0xFFFFFFFFu;
    for (int dz = -1; dz <= 1; ++dz) {
        int z = cz + dz;
        if (z < 0 || z >= K) continue;
        for (int dy = -1; dy <= 1; ++dy) {
            int yy = cy + dy;
            if (yy < 0 || yy >= K) continue;
            int cid = base + (z * K + yy) * K + x0c;
            unsigned s = offs[cid], e = offs[cid + span];
            for (unsigned j = s + lane; j < e; j += W) {
                float4 Pv = pts[j];
                float ddx = Q.x - Pv.x, ddy = Q.y - Pv.y, ddz = Q.z - Pv.z;
                float d2 = fmaf(ddx, ddx, fmaf(ddy, ddy, ddz * ddz));
                unsigned key = ROWS
                    ? ((__float_as_uint(d2) & 0xFFFFE000u) | __float_as_uint(Pv.w))
                    : __float_as_uint(d2);
                best = umin32(best, key);
            }
        }
    }
#pragma unroll
    for (int o = W / 2; o > 0; o >>= 1)
        best = umin32(best, (unsigned)__shfl_xor((int)best, o, 64));
    // certification: exact distance to scanned-box boundary; edge axes open.
    float lox = fmaf((float)cx, H, -R0);
    float loy = fmaf((float)cy, H, -R0);
    float loz = fmaf((float)cz, H, -R0);
    const float INF = __builtin_inff();
    float thr = INF;
    thr = fminf(thr, (cx == 0)     ? INF : Q.x - (lox - H));
    thr = fminf(thr, (cx == K - 1) ? INF : (lox + 2.f * H) - Q.x);
    thr = fminf(thr, (cy == 0)     ? INF : Q.y - (loy - H));
    thr = fminf(thr, (cy == K - 1) ? INF : (loy + 2.f * H) - Q.y);
    thr = fminf(thr, (cz == 0)     ? INF : Q.z - (loz - H));
    thr = fminf(thr, (cz == K - 1) ? INF : (loz + 2.f * H) - Q.z);
    float bd2 = __uint_as_float(ROWS ? (best & 0xFFFFE000u) : best);
    bool certified = (thr > 0.f) && (bd2 <= thr * thr);  // NaN/empty -> false
    if (lane == 0) {
        outv[qi] = best;
        if (!certified) fblist[atomicAdd(&fbcnt[ROWS ? 0 : 1], 1u)] = qi;
    }
}

constexpr int RBLK = NP * 16 / 256;   // 4096 row blocks (W=16)
constexpr int CBLK = MP * 64 / 256;   // 2048 col blocks (W=64)

__global__ __launch_bounds__(256) void k_nn(const float4* __restrict__ pts,
                                            const unsigned* __restrict__ offs,
                                            unsigned* __restrict__ rowkey,
                                            unsigned* __restrict__ colbits,
                                            unsigned* __restrict__ fbcnt,
                                            unsigned* __restrict__ fbrow,
                                            unsigned* __restrict__ fbcol) {
    if (blockIdx.x < CBLK)  // cols FIRST: longest chains start at t=0
        nn_body<64, false>(blockIdx.x, pts, offs, colbits, fbcnt, fbcol);
    else
        nn_body<16, true>(blockIdx.x - CBLK, pts, offs, rowkey, fbcnt, fbrow);
}

// Segmented fallback: wave-task = (query, candidate segment). Rows: 16 segs
// of 512 over the y-run; cols: 64 segs of 1024 over the x-run. Short chains
// (8-16 strided loads), grid-stride over tasks, exact atomicMin merge.
constexpr int RSEG = 16, RSEGLEN = MP / RSEG;    // 512
constexpr int CSEG = 64, CSEGLEN = NP / CSEG;    // 1024

__global__ __launch_bounds__(256) void k_fb(const float* __restrict__ x,
                                            const float* __restrict__ y,
                                            const float4* __restrict__ pts,
                                            const unsigned* __restrict__ fbcnt,
                                            const unsigned* __restrict__ fbrow,
                                            const unsigned* __restrict__ fbcol,
                                            unsigned* __restrict__ rowkey,
                                            unsigned* __restrict__ colbits) {
    int lane = threadIdx.x & 63;
    unsigned wid = (blockIdx.x * 256 + threadIdx.x) >> 6;
    unsigned nw = gridDim.x * 4;
    unsigned nr = fbcnt[0], nc = fbcnt[1];
    unsigned rtasks = nr * RSEG;
    for (unsigned tsk = wid; tsk < rtasks; tsk += nw) {
        unsigned q = tsk / RSEG, seg = tsk % RSEG;
        unsigned n = fbrow[q];
        float qx = x[3 * n], qy = x[3 * n + 1], qz = x[3 * n + 2];
        unsigned best = 0xFFFFFFFFu;
        int s0 = NP + seg * RSEGLEN;
#pragma unroll 2
        for (int s = s0 + lane; s < s0 + RSEGLEN; s += 64) {
            float4 Pv = pts[s];
            float ddx = qx - Pv.x, ddy = qy - Pv.y, ddz = qz - Pv.z;
            float d2 = fmaf(ddx, ddx, fmaf(ddy, ddy, ddz * ddz));
            best = umin32(best, (__float_as_uint(d2) & 0xFFFFE000u) | __float_as_uint(Pv.w));
        }
#pragma unroll
        for (int o = 32; o > 0; o >>= 1)
            best = umin32(best, (unsigned)__shfl_xor((int)best, o, 64));
        if (lane == 0) atomicMin(&rowkey[n], best);
    }
    unsigned ctasks = nc * CSEG;
    for (unsigned tsk = wid; tsk < ctasks; tsk += nw) {
        unsigned q = tsk / CSEG, seg = tsk % CSEG;
        unsigned m = fbcol[q];
        float qx = y[3 * m], qy = y[3 * m + 1], qz = y[3 * m + 2];
        unsigned bb = 0x7F800000u;  // +inf bits; d2 >= 0 so uint order == float order
        int s0 = seg * CSEGLEN;
#pragma unroll 2
        for (int s = s0 + lane; s < s0 + CSEGLEN; s += 64) {
            float4 Pv = pts[s];
            float ddx = qx - Pv.x, ddy = qy - Pv.y, ddz = qz - Pv.z;
            float d2 = fmaf(ddx, ddx, fmaf(ddy, ddy, ddz * ddz));
            bb = umin32(bb, __float_as_uint(d2));
        }
#pragma unroll
        for (int o = 32; o > 0; o >>= 1)
            bb = umin32(bb, (unsigned)__shfl_xor((int)bb, o, 64));
        if (lane == 0) atomicMin(&colbits[m], bb);
    }
}

__global__ __launch_bounds__(256) void k3_reduce(const unsigned* __restrict__ rowkey,
                                                 const unsigned* __restrict__ colbits,
                                                 const float* __restrict__ probs,
                                                 float* __restrict__ out) {
    int i = blockIdx.x * 256 + threadIdx.x;
    float v = 0.f;
    if (i < NP) {
        unsigned k = rowkey[i];
        unsigned idx = k & 0x1FFFu;
        float dmin = __uint_as_float(k & 0xFFFFE000u);
        v = probs[idx] * dmin;  // l2 contribution
    } else {
        int m = i - NP;
        float dmin = __uint_as_float(colbits[m]);
        v = probs[m] * dmin;  // l1 contribution
    }
    for (int off = 32; off > 0; off >>= 1) v += __shfl_down(v, off, 64);
    __shared__ float wsum[4];
    int lane = threadIdx.x & 63;
    int w = threadIdx.x >> 6;
    if (lane == 0) wsum[w] = v;
    __syncthreads();
    if (threadIdx.x == 0) atomicAdd(out, wsum[0] + wsum[1] + wsum[2] + wsum[3]);
}

extern "C" void kernel_launch(void* const* d_in, const int* in_sizes, int n_in,
                              void* d_out, int out_size, void* d_ws, size_t ws_size,
                              hipStream_t stream) {
    const float* x = (const float*)d_in[0];      // [N,3]
    const float* y = (const float*)d_in[1];      // [M,3]
    const float* probs = (const float*)d_in[2];  // [M]
    float* out = (float*)d_out;

    char* ws = (char*)d_ws;
    unsigned* cnt    = (unsigned*)(ws + OFF_CNT);
    unsigned* fbcnt  = (unsigned*)(ws + OFF_FBCNT);
    unsigned* part   = (unsigned*)(ws + OFF_PART);   // also cursor
    unsigned* offs   = (unsigned*)(ws + OFF_OFFS);
    unsigned* bsum   = (unsigned*)(ws + OFF_BSUM);
    unsigned* fbrow  = (unsigned*)(ws + OFF_FBROW);
    unsigned* fbcol  = (unsigned*)(ws + OFF_FBCOL);
    unsigned* rowkey = (unsigned*)(ws + OFF_ROWKEY);
    unsigned* colbits= (unsigned*)(ws + OFF_COLBIT);
    float4*   pts    = (float4*)(ws + OFF_PTS);

    hipMemsetAsync(cnt, 0, OFF_PART, stream);  // cnt + fbcnt region

    constexpr int NB_PTS = (NP + MP) / 256;    // 288
    k_count<<<NB_PTS, 256, 0, stream>>>(x, y, cnt, fbcnt, out);
    k_scan_a<<<2 * KC / 256, 256, 0, stream>>>(cnt, part, bsum);
    k_scan_c<<<2 * KC / 256, 256, 0, stream>>>(cnt, part, offs, bsum);
    k_scatter<<<NB_PTS, 256, 0, stream>>>(x, y, part, pts);
    k_nn<<<RBLK + CBLK, 256, 0, stream>>>(pts, offs, rowkey, colbits, fbcnt, fbrow, fbcol);
    k_fb<<<512, 256, 0, stream>>>(x, y, pts, fbcnt, fbrow, fbcol, rowkey, colbits);
    k3_reduce<<<NB_PTS, 256, 0, stream>>>(rowkey, colbits, probs, out);
}

// Round 24
// 92.606 us; speedup vs baseline: 1.0304x; 1.0304x over previous
//
#include <hip/hip_runtime.h>

// Chamfer distance loss via uniform-grid NN, cooperative W-lane queries,
// certified ring-1 search + segmented wave-task brute-force fallback.
// N=65536 vertices (x), M=8192 samples (y), D=3, points ~ N(0,1)^3.
// l1 = sum_m probs[m] * min_n d2(n,m);  l2 = sum_n probs[argmin_m] * min_m d2.
//
// FINAL CHAMPION (93.2 us, R22) restored verbatim. Rows W=8 / cols W=64,
// cols dispatched first (longest chains start at t=0). 3-dispatch scan.
// Ledger of regressions closing the search: z-slab -35, stealing -200,
// dual-load -7, 1-blk scan -5, scan-fold -1.5, rows W=16 -1, interleave -28.
//
// Grid: K=32 per dim over [-R0,R0), H=0.265625. Both sets counting-sorted into
// one float4 array (x cells [0,KC), y cells [KC,2KC)); .w = original index.
// NN scan: 27 cells as 9 contiguous runs; W lanes stride each run, shfl_xor min.
// Certification: thr = exact distance to scanned-box boundary, edge-open axes.
// Uncertified (Gaussian tail) -> compacted list -> segmented wave-task brute
// force (exact, atomicMin merge). Rows key = (d2bits & ~0x1FFF) | m.

constexpr int NP = 65536;
constexpr int MP = 8192;
constexpr int K = 32;
constexpr int KC = K * K * K;            // 32768 cells per set
constexpr float H = 0.265625f;           // 8.5/32, exact in fp32
constexpr float R0 = 4.25f;

// ws layout (bytes):
constexpr size_t OFF_CNT    = 0;                      // u32[2*KC]
constexpr size_t OFF_FBCNT  = 262144;                 // u32[2] (+pad)
constexpr size_t OFF_PART   = 262160;                 // u32[2*KC], reused as cursor
constexpr size_t OFF_OFFS   = 524304;                 // u32[2*KC+1] (+pad)
constexpr size_t OFF_BSUM   = 786464;                 // u32[256]
constexpr size_t OFF_FBROW  = 787488;                 // u32[NP]
constexpr size_t OFF_FBCOL  = 1049632;                // u32[MP]
constexpr size_t OFF_ROWKEY = 1082400;                // u32[NP]
constexpr size_t OFF_COLBIT = 1344544;                // u32[MP]
constexpr size_t OFF_PTS    = 1377312;                // float4[NP+MP] (16B aligned)

__device__ __forceinline__ int cellof(float v) {
    int c = (int)floorf((v + R0) * (1.0f / H));
    return min(max(c, 0), K - 1);
}
__device__ __forceinline__ unsigned umin32(unsigned a, unsigned b) { return a < b ? a : b; }

__global__ __launch_bounds__(256) void k_count(const float* __restrict__ x,
                                               const float* __restrict__ y,
                                               unsigned* __restrict__ cnt,
                                               unsigned* __restrict__ fbcnt,
                                               float* __restrict__ out) {
    int i = blockIdx.x * 256 + threadIdx.x;
    if (i == 0) { fbcnt[0] = 0; fbcnt[1] = 0; out[0] = 0.f; }
    if (i < NP) {
        int c = (cellof(x[3 * i + 2]) * K + cellof(x[3 * i + 1])) * K + cellof(x[3 * i]);
        atomicAdd(&cnt[c], 1u);
    } else if (i < NP + MP) {
        int j = i - NP;
        int c = (cellof(y[3 * j + 2]) * K + cellof(y[3 * j + 1])) * K + cellof(y[3 * j]);
        atomicAdd(&cnt[KC + c], 1u);
    }
}

template <bool WRITE_BSUM>
__device__ __forceinline__ void block_excl_scan(unsigned v, unsigned* dst, int g,
                                                unsigned* bsum) {
    int t = threadIdx.x;
    unsigned inc = v;
#pragma unroll
    for (int o = 1; o < 64; o <<= 1) {
        unsigned u = __shfl_up(inc, o, 64);
        if ((t & 63) >= o) inc += u;
    }
    __shared__ unsigned wtot[4];
    if ((t & 63) == 63) wtot[t >> 6] = inc;
    __syncthreads();
    unsigned woff = 0;
    for (int w = 0; w < (t >> 6); ++w) woff += wtot[w];
    dst[g] = woff + inc - v;
    if (WRITE_BSUM && t == 255) bsum[blockIdx.x] = woff + inc;
}

__global__ __launch_bounds__(256) void k_scan_a(const unsigned* __restrict__ cnt,
                                                unsigned* __restrict__ part,
                                                unsigned* __restrict__ bsum) {
    int g = blockIdx.x * 256 + threadIdx.x;
    block_excl_scan<true>(cnt[g], part, g, bsum);
}

__global__ __launch_bounds__(256) void k_scan_b(unsigned* __restrict__ bsum) {
    int t = threadIdx.x;
    block_excl_scan<false>(bsum[t], bsum, t, nullptr);
}

__global__ __launch_bounds__(256) void k_scan_c(const unsigned* __restrict__ cnt,
                                                unsigned* __restrict__ part,
                                                unsigned* __restrict__ offs,
                                                const unsigned* __restrict__ bsum) {
    int g = blockIdx.x * 256 + threadIdx.x;
    unsigned off = part[g] + bsum[blockIdx.x];
    offs[g] = off;
    part[g] = off;  // cursor for scatter
    if (g == 2 * KC - 1) offs[2 * KC] = off + cnt[g];
}

__global__ __launch_bounds__(256) void k_scatter(const float* __restrict__ x,
                                                 const float* __restrict__ y,
                                                 unsigned* __restrict__ cursor,
                                                 float4* __restrict__ pts) {
    int i = blockIdx.x * 256 + threadIdx.x;
    if (i < NP) {
        float a = x[3 * i], b = x[3 * i + 1], c = x[3 * i + 2];
        int cc = (cellof(c) * K + cellof(b)) * K + cellof(a);
        unsigned s = atomicAdd(&cursor[cc], 1u);
        pts[s] = make_float4(a, b, c, __uint_as_float((unsigned)i));
    } else if (i < NP + MP) {
        int j = i - NP;
        float a = y[3 * j], b = y[3 * j + 1], c = y[3 * j + 2];
        int cc = (cellof(c) * K + cellof(b)) * K + cellof(a);
        unsigned s = atomicAdd(&cursor[KC + cc], 1u);
        pts[s] = make_float4(a, b, c, __uint_as_float((unsigned)j));
    }
}

// Cooperative NN body: W lanes per query, queries from the cell-sorted pts
// array (W-groups in a wave share a cell -> aligned runs, coalesced loads).
// ROWS: x-queries scan y-cells, packed key with m. COLS: y-queries, d2 bits.
template <int W, bool ROWS>
__device__ __forceinline__ void nn_body(int bid, const float4* __restrict__ pts,
                                        const unsigned* __restrict__ offs,
                                        unsigned* __restrict__ outv,
                                        unsigned* __restrict__ fbcnt,
                                        unsigned* __restrict__ fblist) {
    int t = threadIdx.x;
    int lane = t & (W - 1);
    int q = (bid * 256 + t) / W;
    float4 Q = pts[(ROWS ? 0 : NP) + q];
    unsigned qi = __float_as_uint(Q.w);  // original n (rows) or m (cols)
    int cx = cellof(Q.x), cy = cellof(Q.y), cz = cellof(Q.z);
    int x0c = max(cx - 1, 0), x1c = min(cx + 1, K - 1);
    int span = x1c - x0c + 1;
    constexpr int base = ROWS ? KC : 0;
    unsigned best = 0xFFFFFFFFu;
    for (int dz = -1; dz <= 1; ++dz) {
        int z = cz + dz;
        if (z < 0 || z >= K) continue;
        for (int dy = -1; dy <= 1; ++dy) {
            int yy = cy + dy;
            if (yy < 0 || yy >= K) continue;
            int cid = base + (z * K + yy) * K + x0c;
            unsigned s = offs[cid], e = offs[cid + span];
            for (unsigned j = s + lane; j < e; j += W) {
                float4 Pv = pts[j];
                float ddx = Q.x - Pv.x, ddy = Q.y - Pv.y, ddz = Q.z - Pv.z;
                float d2 = fmaf(ddx, ddx, fmaf(ddy, ddy, ddz * ddz));
                unsigned key = ROWS
                    ? ((__float_as_uint(d2) & 0xFFFFE000u) | __float_as_uint(Pv.w))
                    : __float_as_uint(d2);
                best = umin32(best, key);
            }
        }
    }
#pragma unroll
    for (int o = W / 2; o > 0; o >>= 1)
        best = umin32(best, (unsigned)__shfl_xor((int)best, o, 64));
    // certification: exact distance to scanned-box boundary; edge axes open.
    float lox = fmaf((float)cx, H, -R0);
    float loy = fmaf((float)cy, H, -R0);
    float loz = fmaf((float)cz, H, -R0);
    const float INF = __builtin_inff();
    float thr = INF;
    thr = fminf(thr, (cx == 0)     ? INF : Q.x - (lox - H));
    thr = fminf(thr, (cx == K - 1) ? INF : (lox + 2.f * H) - Q.x);
    thr = fminf(thr, (cy == 0)     ? INF : Q.y - (loy - H));
    thr = fminf(thr, (cy == K - 1) ? INF : (loy + 2.f * H) - Q.y);
    thr = fminf(thr, (cz == 0)     ? INF : Q.z - (loz - H));
    thr = fminf(thr, (cz == K - 1) ? INF : (loz + 2.f * H) - Q.z);
    float bd2 = __uint_as_float(ROWS ? (best & 0xFFFFE000u) : best);
    bool certified = (thr > 0.f) && (bd2 <= thr * thr);  // NaN/empty -> false
    if (lane == 0) {
        outv[qi] = best;
        if (!certified) fblist[atomicAdd(&fbcnt[ROWS ? 0 : 1], 1u)] = qi;
    }
}

constexpr int RBLK = NP * 8 / 256;    // 2048 row blocks (W=8)
constexpr int CBLK = MP * 64 / 256;   // 2048 col blocks (W=64)

__global__ __launch_bounds__(256) void k_nn(const float4* __restrict__ pts,
                                            const unsigned* __restrict__ offs,
                                            unsigned* __restrict__ rowkey,
                                            unsigned* __restrict__ colbits,
                                            unsigned* __restrict__ fbcnt,
                                            unsigned* __restrict__ fbrow,
                                            unsigned* __restrict__ fbcol) {
    if (blockIdx.x < CBLK)  // cols FIRST: longest chains start at t=0
        nn_body<64, false>(blockIdx.x, pts, offs, colbits, fbcnt, fbcol);
    else
        nn_body<8, true>(blockIdx.x - CBLK, pts, offs, rowkey, fbcnt, fbrow);
}

// Segmented fallback: wave-task = (query, candidate segment). Rows: 16 segs
// of 512 over the y-run; cols: 64 segs of 1024 over the x-run. Short chains
// (8-16 strided loads), grid-stride over tasks, exact atomicMin merge.
constexpr int RSEG = 16, RSEGLEN = MP / RSEG;    // 512
constexpr int CSEG = 64, CSEGLEN = NP / CSEG;    // 1024

__global__ __launch_bounds__(256) void k_fb(const float* __restrict__ x,
                                            const float* __restrict__ y,
                                            const float4* __restrict__ pts,
                                            const unsigned* __restrict__ fbcnt,
                                            const unsigned* __restrict__ fbrow,
                                            const unsigned* __restrict__ fbcol,
                                            unsigned* __restrict__ rowkey,
                                            unsigned* __restrict__ colbits) {
    int lane = threadIdx.x & 63;
    unsigned wid = (blockIdx.x * 256 + threadIdx.x) >> 6;
    unsigned nw = gridDim.x * 4;
    unsigned nr = fbcnt[0], nc = fbcnt[1];
    unsigned rtasks = nr * RSEG;
    for (unsigned tsk = wid; tsk < rtasks; tsk += nw) {
        unsigned q = tsk / RSEG, seg = tsk % RSEG;
        unsigned n = fbrow[q];
        float qx = x[3 * n], qy = x[3 * n + 1], qz = x[3 * n + 2];
        unsigned best = 0xFFFFFFFFu;
        int s0 = NP + seg * RSEGLEN;
#pragma unroll 2
        for (int s = s0 + lane; s < s0 + RSEGLEN; s += 64) {
            float4 Pv = pts[s];
            float ddx = qx - Pv.x, ddy = qy - Pv.y, ddz = qz - Pv.z;
            float d2 = fmaf(ddx, ddx, fmaf(ddy, ddy, ddz * ddz));
            best = umin32(best, (__float_as_uint(d2) & 0xFFFFE000u) | __float_as_uint(Pv.w));
        }
#pragma unroll
        for (int o = 32; o > 0; o >>= 1)
            best = umin32(best, (unsigned)__shfl_xor((int)best, o, 64));
        if (lane == 0) atomicMin(&rowkey[n], best);
    }
    unsigned ctasks = nc * CSEG;
    for (unsigned tsk = wid; tsk < ctasks; tsk += nw) {
        unsigned q = tsk / CSEG, seg = tsk % CSEG;
        unsigned m = fbcol[q];
        float qx = y[3 * m], qy = y[3 * m + 1], qz = y[3 * m + 2];
        unsigned bb = 0x7F800000u;  // +inf bits; d2 >= 0 so uint order == float order
        int s0 = seg * CSEGLEN;
#pragma unroll 2
        for (int s = s0 + lane; s < s0 + CSEGLEN; s += 64) {
            float4 Pv = pts[s];
            float ddx = qx - Pv.x, ddy = qy - Pv.y, ddz = qz - Pv.z;
            float d2 = fmaf(ddx, ddx, fmaf(ddy, ddy, ddz * ddz));
            bb = umin32(bb, __float_as_uint(d2));
        }
#pragma unroll
        for (int o = 32; o > 0; o >>= 1)
            bb = umin32(bb, (unsigned)__shfl_xor((int)bb, o, 64));
        if (lane == 0) atomicMin(&colbits[m], bb);
    }
}

__global__ __launch_bounds__(256) void k3_reduce(const unsigned* __restrict__ rowkey,
                                                 const unsigned* __restrict__ colbits,
                                                 const float* __restrict__ probs,
                                                 float* __restrict__ out) {
    int i = blockIdx.x * 256 + threadIdx.x;
    float v = 0.f;
    if (i < NP) {
        unsigned k = rowkey[i];
        unsigned idx = k & 0x1FFFu;
        float dmin = __uint_as_float(k & 0xFFFFE000u);
        v = probs[idx] * dmin;  // l2 contribution
    } else {
        int m = i - NP;
        float dmin = __uint_as_float(colbits[m]);
        v = probs[m] * dmin;  // l1 contribution
    }
    for (int off = 32; off > 0; off >>= 1) v += __shfl_down(v, off, 64);
    __shared__ float wsum[4];
    int lane = threadIdx.x & 63;
    int w = threadIdx.x >> 6;
    if (lane == 0) wsum[w] = v;
    __syncthreads();
    if (threadIdx.x == 0) atomicAdd(out, wsum[0] + wsum[1] + wsum[2] + wsum[3]);
}

extern "C" void kernel_launch(void* const* d_in, const int* in_sizes, int n_in,
                              void* d_out, int out_size, void* d_ws, size_t ws_size,
                              hipStream_t stream) {
    const float* x = (const float*)d_in[0];      // [N,3]
    const float* y = (const float*)d_in[1];      // [M,3]
    const float* probs = (const float*)d_in[2];  // [M]
    float* out = (float*)d_out;

    char* ws = (char*)d_ws;
    unsigned* cnt    = (unsigned*)(ws + OFF_CNT);
    unsigned* fbcnt  = (unsigned*)(ws + OFF_FBCNT);
    unsigned* part   = (unsigned*)(ws + OFF_PART);   // also cursor
    unsigned* offs   = (unsigned*)(ws + OFF_OFFS);
    unsigned* bsum   = (unsigned*)(ws + OFF_BSUM);
    unsigned* fbrow  = (unsigned*)(ws + OFF_FBROW);
    unsigned* fbcol  = (unsigned*)(ws + OFF_FBCOL);
    unsigned* rowkey = (unsigned*)(ws + OFF_ROWKEY);
    unsigned* colbits= (unsigned*)(ws + OFF_COLBIT);
    float4*   pts    = (float4*)(ws + OFF_PTS);

    hipMemsetAsync(cnt, 0, OFF_PART, stream);  // cnt + fbcnt region

    constexpr int NB_PTS = (NP + MP) / 256;    // 288
    k_count<<<NB_PTS, 256, 0, stream>>>(x, y, cnt, fbcnt, out);
    k_scan_a<<<2 * KC / 256, 256, 0, stream>>>(cnt, part, bsum);
    k_scan_b<<<1, 256, 0, stream>>>(bsum);
    k_scan_c<<<2 * KC / 256, 256, 0, stream>>>(cnt, part, offs, bsum);
    k_scatter<<<NB_PTS, 256, 0, stream>>>(x, y, part, pts);
    k_nn<<<RBLK + CBLK, 256, 0, stream>>>(pts, offs, rowkey, colbits, fbcnt, fbrow, fbcol);
    k_fb<<<512, 256, 0, stream>>>(x, y, pts, fbcnt, fbrow, fbcol, rowkey, colbits);
    k3_reduce<<<NB_PTS, 256, 0, stream>>>(rowkey, colbits, probs, out);
}